// Round 2
// baseline (502.715 us; speedup 1.0000x reference)
//
#include <hip/hip_runtime.h>

// ---------------------------------------------------------------------------
// HierarchicalRegimeController on MI355X — fp32 in/out.
// 4-kernel structure (resubmission; round-1 bench was an infra failure):
//   KA k_partial : x partial sums, 2048 blocks (32 waves/CU, max occupancy)
//   KB k_gemm1act: chunk-reduce + diff + 3x GEMM(512x512) + LN + GELU fused
//   KC k_gemm2   : second-layer GEMMs, float2 weight loads (new this round)
//   KD k_final   : gumbel-softmax + KL + gates + ticket-fused scalar epilogue
// PRNG: JAX threefry2x32, jax_threefry_partitionable=True.
// ---------------------------------------------------------------------------

#define NB 64     // batch
#define NT 2048   // seq
#define ND 512    // d_model
#define NH 512    // hidden
#define NG 4
#define NS 6
#define NA 4

typedef unsigned int u32;

// ---------------- threefry2x32 (JAX-exact, 20 rounds) ----------------------
struct TF2 { u32 a, b; };

__host__ __device__ constexpr u32 rotl32(u32 x, int r) { return (x << r) | (x >> (32 - r)); }

__host__ __device__ constexpr TF2 tf2x32(u32 k0, u32 k1, u32 x0, u32 x1) {
  u32 ks2 = k0 ^ k1 ^ 0x1BD11BDAu;
  x0 += k0; x1 += k1;
  x0 += x1; x1 = rotl32(x1, 13); x1 ^= x0;
  x0 += x1; x1 = rotl32(x1, 15); x1 ^= x0;
  x0 += x1; x1 = rotl32(x1, 26); x1 ^= x0;
  x0 += x1; x1 = rotl32(x1, 6);  x1 ^= x0;
  x0 += k1;  x1 += ks2 + 1u;
  x0 += x1; x1 = rotl32(x1, 17); x1 ^= x0;
  x0 += x1; x1 = rotl32(x1, 29); x1 ^= x0;
  x0 += x1; x1 = rotl32(x1, 16); x1 ^= x0;
  x0 += x1; x1 = rotl32(x1, 24); x1 ^= x0;
  x0 += ks2; x1 += k0 + 2u;
  x0 += x1; x1 = rotl32(x1, 13); x1 ^= x0;
  x0 += x1; x1 = rotl32(x1, 15); x1 ^= x0;
  x0 += x1; x1 = rotl32(x1, 26); x1 ^= x0;
  x0 += x1; x1 = rotl32(x1, 6);  x1 ^= x0;
  x0 += k0;  x1 += k1 + 3u;
  x0 += x1; x1 = rotl32(x1, 17); x1 ^= x0;
  x0 += x1; x1 = rotl32(x1, 29); x1 ^= x0;
  x0 += x1; x1 = rotl32(x1, 16); x1 ^= x0;
  x0 += x1; x1 = rotl32(x1, 24); x1 ^= x0;
  x0 += k1;  x1 += ks2 + 4u;
  x0 += x1; x1 = rotl32(x1, 13); x1 ^= x0;
  x0 += x1; x1 = rotl32(x1, 15); x1 ^= x0;
  x0 += x1; x1 = rotl32(x1, 26); x1 ^= x0;
  x0 += x1; x1 = rotl32(x1, 6);  x1 ^= x0;
  x0 += ks2; x1 += k0 + 5u;
  return TF2{x0, x1};
}

constexpr TF2 GKG = tf2x32(0u, 42u, 0u, 0u);  // global gumbel key
constexpr TF2 GKS = tf2x32(0u, 42u, 0u, 1u);  // sector
constexpr TF2 GKA = tf2x32(0u, 42u, 0u, 2u);  // asset

__device__ inline float gumbel32(u32 k0, u32 k1, u32 idx) {
  TF2 r = tf2x32(k0, k1, 0u, idx);
  u32 bits = r.a ^ r.b;
  float f = __uint_as_float((bits >> 9) | 0x3f800000u) - 1.0f;  // [0,1)
  f = fmaxf(f, 1.17549435e-38f);
  return -logf(-logf(f));
}

__device__ inline float gelu_exact(float x) {
  return 0.5f * x * (1.0f + erff(x * 0.70710678118654752f));
}

// ---------------- KA: partial sums over T ----------------------------------
// grid 2048 = B(64) x 32 chunks of 64 rows; block 256 = 4 waves.
// 2048 blocks x 4 waves / 256 CU = 32 waves/CU (max occupancy);
// __launch_bounds__(256,8) caps VGPR at 64 so all 8 blocks/CU are resident.
__global__ __launch_bounds__(256, 8) void k_partial(const float* __restrict__ x,
                                                    float* __restrict__ part,
                                                    float* __restrict__ klacc) {
  if (blockIdx.x == 0 && threadIdx.x < 4) klacc[threadIdx.x] = 0.0f;  // [3] = ticket
  int bx = blockIdx.x;
  int b = bx >> 5, c = bx & 31;
  int tid = threadIdx.x;
  int q = tid & 127;   // which 4-col quad
  int rg = tid >> 7;   // row group 0/1
  const float* base = x + ((size_t)(b * NT + c * 64 + rg) * ND + q * 4);
  float4 acc = make_float4(0.f, 0.f, 0.f, 0.f);
#pragma unroll 8
  for (int i = 0; i < 32; ++i) {
    float4 v = *reinterpret_cast<const float4*>(base + (size_t)i * 2 * ND);
    acc.x += v.x; acc.y += v.y; acc.z += v.z; acc.w += v.w;
  }
  __shared__ float sm[2][ND];
  *reinterpret_cast<float4*>(&sm[rg][q * 4]) = acc;
  __syncthreads();
  float* p = part + (size_t)bx * ND;
  p[tid]       = sm[0][tid] + sm[1][tid];
  p[tid + 256] = sm[0][tid + 256] + sm[1][tid + 256];
}

// ---------------- KB: finalize means + first-layer GEMMs + LN + GELU -------
// grid 96 = mu(3) x mtile(32 of 2 batch rows); block 256.
// Each thread owns 2 consecutive cols for both rows (4 accumulators).
// mu==0: LayerNorm(row over 512) then GELU; mu 1/2: GELU only.
__global__ __launch_bounds__(256) void k_gemm1act(
    const float* __restrict__ part, const float* __restrict__ x,
    const float* __restrict__ gW1, const float* __restrict__ gb1,
    const float* __restrict__ g_ln_w, const float* __restrict__ g_ln_b,
    const float* __restrict__ sW1, const float* __restrict__ sb1,
    const float* __restrict__ aW1, const float* __restrict__ ab1,
    float* __restrict__ act) {
  int bx = blockIdx.x;
  int mu = bx >> 5;          // 0:global 1:sector 2:asset
  int m0 = (bx & 31) * 2;    // batch row pair
  const float* W    = (mu == 0) ? gW1 : (mu == 1) ? sW1 : aW1;
  const float* bias = (mu == 0) ? gb1 : (mu == 1) ? sb1 : ab1;
  int tid = threadIdx.x;
  int colp = tid * 2;

  __shared__ float2 As[ND];  // As[k] = {A[m0][k], A[m0+1][k]}
  if (mu < 2) {
    // seq_mean: reduce the 32 row-chunk partials
    const float* p0 = part + (size_t)m0 * 32 * ND + colp;
    const float* p1 = part + (size_t)(m0 + 1) * 32 * ND + colp;
    float2 s0 = make_float2(0.f, 0.f), s1 = make_float2(0.f, 0.f);
#pragma unroll 8
    for (int c = 0; c < 32; ++c) {
      float2 v0 = *reinterpret_cast<const float2*>(p0 + (size_t)c * ND);
      float2 v1 = *reinterpret_cast<const float2*>(p1 + (size_t)c * ND);
      s0.x += v0.x; s0.y += v0.y; s1.x += v1.x; s1.y += v1.y;
    }
    const float inv = 1.0f / (float)NT;
    As[colp]     = make_float2(s0.x * inv, s1.x * inv);
    As[colp + 1] = make_float2(s0.y * inv, s1.y * inv);
  } else {
    // diff summary telescopes to (x[last] - x[first]) / (NT-1)
    const float inv = 1.0f / (float)(NT - 1);
    const float* xr0 = x + (size_t)m0 * NT * ND + colp;
    const float* xr1 = x + (size_t)(m0 + 1) * NT * ND + colp;
    float2 f0 = *reinterpret_cast<const float2*>(xr0);
    float2 l0 = *reinterpret_cast<const float2*>(xr0 + (size_t)(NT - 1) * ND);
    float2 f1 = *reinterpret_cast<const float2*>(xr1);
    float2 l1 = *reinterpret_cast<const float2*>(xr1 + (size_t)(NT - 1) * ND);
    As[colp]     = make_float2((l0.x - f0.x) * inv, (l1.x - f1.x) * inv);
    As[colp + 1] = make_float2((l0.y - f0.y) * inv, (l1.y - f1.y) * inv);
  }
  __syncthreads();

  float2 acc0 = make_float2(0.f, 0.f), acc1 = make_float2(0.f, 0.f);
#pragma unroll 8
  for (int k = 0; k < ND; ++k) {
    float2 wv = *reinterpret_cast<const float2*>(&W[(size_t)k * NH + colp]);
    float2 a = As[k];            // broadcast ds_read_b64
    acc0.x += a.x * wv.x; acc0.y += a.x * wv.y;
    acc1.x += a.y * wv.x; acc1.y += a.y * wv.y;
  }
  float2 bb = *reinterpret_cast<const float2*>(&bias[colp]);
  acc0.x += bb.x; acc0.y += bb.y;
  acc1.x += bb.x; acc1.y += bb.y;

  float* arow0 = act + (size_t)m0 * 1536 + mu * 512;
  float* arow1 = act + (size_t)(m0 + 1) * 1536 + mu * 512;

  if (mu == 0) {
    __shared__ float red[2][4];
    __shared__ float mv[4];
    int wid = tid >> 6, lane = tid & 63;
    // mean
    float s0 = acc0.x + acc0.y, s1 = acc1.x + acc1.y;
#pragma unroll
    for (int o = 32; o > 0; o >>= 1) {
      s0 += __shfl_down(s0, o, 64);
      s1 += __shfl_down(s1, o, 64);
    }
    if (lane == 0) { red[0][wid] = s0; red[1][wid] = s1; }
    __syncthreads();
    if (tid == 0) {
      mv[0] = (red[0][0] + red[0][1] + red[0][2] + red[0][3]) * (1.0f / 512.0f);
      mv[1] = (red[1][0] + red[1][1] + red[1][2] + red[1][3]) * (1.0f / 512.0f);
    }
    __syncthreads();
    float m0v = mv[0], m1v = mv[1];
    float d0x = acc0.x - m0v, d0y = acc0.y - m0v;
    float d1x = acc1.x - m1v, d1y = acc1.y - m1v;
    // var
    float q0 = d0x * d0x + d0y * d0y, q1 = d1x * d1x + d1y * d1y;
#pragma unroll
    for (int o = 32; o > 0; o >>= 1) {
      q0 += __shfl_down(q0, o, 64);
      q1 += __shfl_down(q1, o, 64);
    }
    if (lane == 0) { red[0][wid] = q0; red[1][wid] = q1; }
    __syncthreads();
    if (tid == 0) {
      mv[2] = (red[0][0] + red[0][1] + red[0][2] + red[0][3]) * (1.0f / 512.0f);
      mv[3] = (red[1][0] + red[1][1] + red[1][2] + red[1][3]) * (1.0f / 512.0f);
    }
    __syncthreads();
    float r0 = 1.0f / sqrtf(mv[2] + 1e-5f);
    float r1 = 1.0f / sqrtf(mv[3] + 1e-5f);
    float2 lw = *reinterpret_cast<const float2*>(&g_ln_w[colp]);
    float2 lb = *reinterpret_cast<const float2*>(&g_ln_b[colp]);
    arow0[colp]     = gelu_exact(d0x * r0 * lw.x + lb.x);
    arow0[colp + 1] = gelu_exact(d0y * r0 * lw.y + lb.y);
    arow1[colp]     = gelu_exact(d1x * r1 * lw.x + lb.x);
    arow1[colp + 1] = gelu_exact(d1y * r1 * lw.y + lb.y);
  } else {
    arow0[colp]     = gelu_exact(acc0.x);
    arow0[colp + 1] = gelu_exact(acc0.y);
    arow1[colp]     = gelu_exact(acc1.x);
    arow1[colp + 1] = gelu_exact(acc1.y);
  }
}

// ---------------- KC: second-layer GEMMs (logits) --------------------------
// grid 328 = mtile(8 of 8 rows) x 41 ntiles (g:1, s:24, a:16); block 256.
// Each thread: 2 rows x 2 consecutive cols; W loads are float2 (8 B/lane).
__global__ __launch_bounds__(256) void k_gemm2(
    const float* __restrict__ act,
    const float* __restrict__ gW2, const float* __restrict__ gb2,
    const float* __restrict__ sW2, const float* __restrict__ sb2,
    const float* __restrict__ aW2, const float* __restrict__ ab2,
    float* __restrict__ lg, float* __restrict__ ls, float* __restrict__ la) {
  int bx = blockIdx.x;
  int mt = bx / 41, j = bx % 41;
  int mu, n0, N; const float *W, *bias; float* out;
  if (j == 0)       { mu = 0; n0 = 0;              N = NG;   W = gW2; bias = gb2; out = lg; }
  else if (j <= 24) { mu = 1; n0 = (j - 1) * 128;  N = 3072; W = sW2; bias = sb2; out = ls; }
  else              { mu = 2; n0 = (j - 25) * 128; N = 2048; W = aW2; bias = ab2; out = la; }
  int m0 = mt * 8;
  __shared__ float As[8][NH];
  int tid = threadIdx.x;
  for (int r = 0; r < 16; ++r) {
    int idx = r * 256 + tid;
    As[idx >> 9][idx & 511] = act[(size_t)(m0 + (idx >> 9)) * 1536 + mu * 512 + (idx & 511)];
  }
  __syncthreads();
  int nl = (tid & 63) * 2;
  int ml = (tid >> 6) * 2;
  if (nl < N) {
    int n = n0 + nl;
    float2 a0 = make_float2(0.f, 0.f), a1 = make_float2(0.f, 0.f);
#pragma unroll 8
    for (int k = 0; k < NH; ++k) {
      float2 w = *reinterpret_cast<const float2*>(&W[(size_t)k * N + n]);
      float s0 = As[ml][k], s1 = As[ml + 1][k];
      a0.x += s0 * w.x; a0.y += s0 * w.y;
      a1.x += s1 * w.x; a1.y += s1 * w.y;
    }
    float2 bb = *reinterpret_cast<const float2*>(&bias[n]);
    a0.x += bb.x; a0.y += bb.y;
    a1.x += bb.x; a1.y += bb.y;
    *reinterpret_cast<float2*>(&out[(size_t)(m0 + ml) * N + n])     = a0;
    *reinterpret_cast<float2*>(&out[(size_t)(m0 + ml + 1) * N + n]) = a1;
  }
}

// ---------------- KD: gumbel-softmax + KL + gates + scalar epilogue --------
// grid 256 = b(64) x fq(4); block 128 (one thread per feature f).
// Last block (device-scope ticket on klacc[3]) writes the 3 KL scalars.
__global__ __launch_bounds__(128) void k_final(
    const float* __restrict__ lg, const float* __restrict__ ls,
    const float* __restrict__ la,
    const float* __restrict__ g_prior, const float* __restrict__ s_prior,
    const float* __restrict__ a_prior, const float* __restrict__ g2f,
    const float* __restrict__ semb, const float* __restrict__ aemb,
    float* __restrict__ out, float* __restrict__ klacc) {
  int bx = blockIdx.x;
  int b = bx >> 2, fq = bx & 3;
  int tid = threadIdx.x;
  __shared__ float gp[NG];
  if (tid == 0) {
    float l[NG], z[NG];
    float zm = -1e30f;
#pragma unroll
    for (int g = 0; g < NG; ++g) {
      l[g] = lg[b * NG + g];
      float gn = gumbel32(GKG.a, GKG.b, (u32)(b * NG + g));
      z[g] = (l[g] + gn) * 2.0f;  // /tau, tau=0.5
      zm = fmaxf(zm, z[g]);
    }
    float zs = 0.f;
#pragma unroll
    for (int g = 0; g < NG; ++g) { z[g] = expf(z[g] - zm); zs += z[g]; }
    float inv = 1.0f / zs;
#pragma unroll
    for (int g = 0; g < NG; ++g) gp[g] = z[g] * inv;
    if (fq == 0) {
#pragma unroll
      for (int g = 0; g < NG; ++g) out[b * NG + g] = gp[g];
      float lm = -1e30f, qm = -1e30f, q[NG];
#pragma unroll
      for (int g = 0; g < NG; ++g) {
        q[g] = g_prior[g];
        lm = fmaxf(lm, l[g]); qm = fmaxf(qm, q[g]);
      }
      float le = 0.f, qe = 0.f;
#pragma unroll
      for (int g = 0; g < NG; ++g) { le += expf(l[g] - lm); qe += expf(q[g] - qm); }
      float lls = logf(le), qls = logf(qe);
      float kl = 0.f;
#pragma unroll
      for (int g = 0; g < NG; ++g) {
        float lp = l[g] - lm - lls, lq = q[g] - qm - qls;
        kl += expf(lp) * (lp - lq);
      }
      atomicAdd(&klacc[0], kl);
    }
  }
  __syncthreads();
  int f = fq * 128 + tid;

  // ---- sector (6-way) ----
  float sl[NS], sz[NS], sp[NS];
  u32 sbase = (u32)((b * ND + f) * NS);
  const float* lsp = ls + (size_t)b * 3072 + f * NS;
  float zm = -1e30f;
#pragma unroll
  for (int s = 0; s < NS; ++s) {
    sl[s] = lsp[s];
    float gn = gumbel32(GKS.a, GKS.b, sbase + s);
    sz[s] = (sl[s] + gn) * 2.0f;
    zm = fmaxf(zm, sz[s]);
  }
  float zs = 0.f;
#pragma unroll
  for (int s = 0; s < NS; ++s) { sz[s] = expf(sz[s] - zm); zs += sz[s]; }
  float inv = 1.0f / zs;
  float* outs = out + 256 + (size_t)sbase;
#pragma unroll
  for (int s = 0; s < NS; ++s) { sp[s] = sz[s] * inv; outs[s] = sp[s]; }
  // KL sector
  float lm = -1e30f;
#pragma unroll
  for (int s = 0; s < NS; ++s) lm = fmaxf(lm, sl[s]);
  float le = 0.f;
#pragma unroll
  for (int s = 0; s < NS; ++s) le += expf(sl[s] - lm);
  float lls = logf(le);
  float q6[NS], qm = -1e30f;
#pragma unroll
  for (int s = 0; s < NS; ++s) { q6[s] = s_prior[s]; qm = fmaxf(qm, q6[s]); }
  float qe = 0.f;
#pragma unroll
  for (int s = 0; s < NS; ++s) qe += expf(q6[s] - qm);
  float qls = logf(qe);
  float klS = 0.f;
#pragma unroll
  for (int s = 0; s < NS; ++s) {
    float lp = sl[s] - lm - lls, lq = q6[s] - qm - qls;
    klS += expf(lp) * (lp - lq);
  }

  // ---- asset (4-way) ----
  float al[NA], az[NA], ap[NA];
  u32 abase = (u32)((b * ND + f) * NA);
  const float* lap = la + (size_t)b * 2048 + f * NA;
  zm = -1e30f;
#pragma unroll
  for (int a = 0; a < NA; ++a) {
    al[a] = lap[a];
    float gn = gumbel32(GKA.a, GKA.b, abase + a);
    az[a] = (al[a] + gn) * 2.0f;
    zm = fmaxf(zm, az[a]);
  }
  zs = 0.f;
#pragma unroll
  for (int a = 0; a < NA; ++a) { az[a] = expf(az[a] - zm); zs += az[a]; }
  inv = 1.0f / zs;
  float* outa = out + 196864 + (size_t)abase;
#pragma unroll
  for (int a = 0; a < NA; ++a) { ap[a] = az[a] * inv; outa[a] = ap[a]; }
  // KL asset
  lm = -1e30f;
#pragma unroll
  for (int a = 0; a < NA; ++a) lm = fmaxf(lm, al[a]);
  le = 0.f;
#pragma unroll
  for (int a = 0; a < NA; ++a) le += expf(al[a] - lm);
  lls = logf(le);
  float q4[NA]; qm = -1e30f;
#pragma unroll
  for (int a = 0; a < NA; ++a) { q4[a] = a_prior[a]; qm = fmaxf(qm, q4[a]); }
  qe = 0.f;
#pragma unroll
  for (int a = 0; a < NA; ++a) qe += expf(q4[a] - qm);
  qls = logf(qe);
  float klA = 0.f;
#pragma unroll
  for (int a = 0; a < NA; ++a) {
    float lp = al[a] - lm - lls, lq = q4[a] - qm - qls;
    klA += expf(lp) * (lp - lq);
  }

  // ---- gates ----
  float gg = 0.f;
#pragma unroll
  for (int g = 0; g < NG; ++g) gg += gp[g] * g2f[g * ND + f];
  float sg = 0.f;
#pragma unroll
  for (int s = 0; s < NS; ++s) sg += sp[s] * semb[s * ND + f];
  float ag = 0.f;
#pragma unroll
  for (int a = 0; a < NA; ++a) ag += ap[a] * aemb[a * ND + f];
  float xg = gg + sg + ag;
  out[327936 + b * ND + f] = 1.0f / (1.0f + expf(-xg));

  // ---- KL reductions (per-wave shuffle, then one atomic per wave) ----
#pragma unroll
  for (int o = 32; o > 0; o >>= 1) {
    klS += __shfl_down(klS, o, 64);
    klA += __shfl_down(klA, o, 64);
  }
  if ((tid & 63) == 0) {
    atomicAdd(&klacc[1], klS);
    atomicAdd(&klacc[2], klA);
  }

  // ---- ticket-fused scalar epilogue (replaces a 5th launch) ----
  __syncthreads();     // all this block's atomics issued
  __threadfence();     // order them before the ticket (device scope)
  if (tid == 0) {
    u32 old = atomicAdd(reinterpret_cast<u32*>(&klacc[3]), 1u);
    if (old == 255u) {            // last of 256 blocks
      __threadfence();
      float kg  = atomicAdd(&klacc[0], 0.0f);   // device-coherent reads
      float ksv = atomicAdd(&klacc[1], 0.0f);
      float kav = atomicAdd(&klacc[2], 0.0f);
      out[360704] = kg  * (1.0f / 64.0f);
      out[360705] = ksv * (1.0f / 32768.0f);
      out[360706] = kav * (1.0f / 32768.0f);
    }
  }
}

// ---------------------------------------------------------------------------
extern "C" void kernel_launch(void* const* d_in, const int* in_sizes, int n_in,
                              void* d_out, int out_size, void* d_ws, size_t ws_size,
                              hipStream_t stream) {
  const float* x       = (const float*)d_in[0];
  const float* gW1     = (const float*)d_in[1];
  const float* gb1     = (const float*)d_in[2];
  const float* g_ln_w  = (const float*)d_in[3];
  const float* g_ln_b  = (const float*)d_in[4];
  const float* gW2     = (const float*)d_in[5];
  const float* gb2     = (const float*)d_in[6];
  const float* sW1     = (const float*)d_in[7];
  const float* sb1     = (const float*)d_in[8];
  const float* sW2     = (const float*)d_in[9];
  const float* sb2     = (const float*)d_in[10];
  const float* aW1     = (const float*)d_in[11];
  const float* ab1     = (const float*)d_in[12];
  const float* aW2     = (const float*)d_in[13];
  const float* ab2     = (const float*)d_in[14];
  const float* g_prior = (const float*)d_in[15];
  const float* s_prior = (const float*)d_in[16];
  const float* a_prior = (const float*)d_in[17];
  const float* g2f     = (const float*)d_in[18];
  const float* semb    = (const float*)d_in[19];
  const float* aemb    = (const float*)d_in[20];

  float* ws    = (float*)d_ws;
  float* part  = ws;                   // 2048*512      = 1,048,576
  float* act   = part + 1048576;       // 64*1536       =    98,304
  float* lg    = act + 98304;          // 64*4          =       256
  float* ls    = lg + 256;             // 64*3072       =   196,608
  float* la    = ls + 196608;          // 64*2048       =   131,072
  float* klacc = la + 131072;          // 4 (klacc[3] = ticket counter)

  float* out = (float*)d_out;

  hipLaunchKernelGGL(k_partial,  dim3(2048), dim3(256), 0, stream, x, part, klacc);
  hipLaunchKernelGGL(k_gemm1act, dim3(96),   dim3(256), 0, stream,
                     part, x, gW1, gb1, g_ln_w, g_ln_b, sW1, sb1, aW1, ab1, act);
  hipLaunchKernelGGL(k_gemm2,    dim3(328),  dim3(256), 0, stream,
                     act, gW2, gb2, sW2, sb2, aW2, ab2, lg, ls, la);
  hipLaunchKernelGGL(k_final,    dim3(256),  dim3(128), 0, stream,
                     lg, ls, la, g_prior, s_prior, a_prior, g2f, semb, aemb, out, klacc);
}